// Round 11
// baseline (2812.083 us; speedup 1.0000x reference)
//
#include <hip/hip_runtime.h>
#include <hip/hip_fp16.h>
#include <math.h>

#define BB 2
#define DD 256
#define HH 8
#define HDIM 32
#define FFD 1024
#define LL 6
#define NQQ 540
#define QPO_ 27
#define PS0 20
#define PS1 20
#define PS2 32
#define PP (PS0*PS1*PS2)   // 12800
#define MR (BB*NQQ)        // 1080
#define NSPL 4             // cross-attn row-partials per query

typedef _Float16 half8 __attribute__((ext_vector_type(8)));
typedef _Float16 h2v  __attribute__((ext_vector_type(2)));
typedef float f32x4 __attribute__((ext_vector_type(4)));

static __device__ __forceinline__ float wred_sum(float x) {
#pragma unroll
  for (int off = 32; off; off >>= 1) x += __shfl_xor(x, off, 64);
  return x;
}
static __device__ __forceinline__ float wred_max(float x) {
#pragma unroll
  for (int off = 32; off; off >>= 1) x = fmaxf(x, __shfl_xor(x, off, 64));
  return x;
}
static __device__ __forceinline__ float4 h4_to_f4(uint2 u) {
  __half2 h0 = *reinterpret_cast<__half2*>(&u.x);
  __half2 h1 = *reinterpret_cast<__half2*>(&u.y);
  float2 f0 = __half22float2(h0);
  float2 f1 = __half22float2(h1);
  return make_float4(f0.x, f0.y, f1.x, f1.y);
}

// ---------------------------------------------------------------------------
// init: tgt[b,q,d] = qe[q, 256+d]; qpos[b,q,d] = qe[q, d]
__global__ __launch_bounds__(256) void init_kernel(
    const float* __restrict__ qe, float* __restrict__ tgt, float* __restrict__ qpos)
{
  int idx = blockIdx.x * 256 + threadIdx.x;   // < B*NQ*D == 276480
  int d = idx % DD;
  int q = (idx / DD) % NQQ;
  qpos[idx] = qe[q * 512 + d];
  tgt[idx]  = qe[q * 512 + 256 + d];
}

// ---------------------------------------------------------------------------
// One-time: transpose+convert src/pos to fp16 [b][p][d] layouts.
__global__ __launch_bounds__(256) void conv_kv_inputs(
    const float* __restrict__ src, const float* __restrict__ pos,
    __half* __restrict__ s16, __half* __restrict__ kv16)
{
  __shared__ float ls[64][65];
  __shared__ float lk[64][65];
  int b  = blockIdx.z;
  int p0 = blockIdx.x * 64;
  int d0 = blockIdx.y * 64;
  int t = threadIdx.x;
  int pr = (t & 15) * 4;
  int dr = t >> 4;
#pragma unroll
  for (int dd = 0; dd < 64; dd += 16) {
    int d = d0 + dd + dr;
    float4 sv = *(const float4*)&src[((size_t)b * DD + d) * PP + p0 + pr];
    float4 pv = *(const float4*)&pos[((size_t)b * DD + d) * PP + p0 + pr];
    ls[pr + 0][dd + dr] = sv.x; ls[pr + 1][dd + dr] = sv.y;
    ls[pr + 2][dd + dr] = sv.z; ls[pr + 3][dd + dr] = sv.w;
    lk[pr + 0][dd + dr] = sv.x + pv.x; lk[pr + 1][dd + dr] = sv.y + pv.y;
    lk[pr + 2][dd + dr] = sv.z + pv.z; lk[pr + 3][dd + dr] = sv.w + pv.w;
  }
  __syncthreads();
  int wp = t >> 2;
  int wd = (t & 3) * 16;
  size_t base = ((size_t)b * PP + p0 + wp) * 256 + d0 + wd;
#pragma unroll
  for (int i = 0; i < 16; i += 2) {
    *(__half2*)&s16[base + i]  = __floats2half2_rn(ls[wp][wd + i], ls[wp][wd + i + 1]);
    *(__half2*)&kv16[base + i] = __floats2half2_rn(lk[wp][wd + i], lk[wp][wd + i + 1]);
  }
}

// One-time: fp32 -> fp16 weight conversion (grid-stride).
__global__ __launch_bounds__(256) void conv_w(
    const float* __restrict__ w, __half* __restrict__ w16, int n)
{
  for (int i = blockIdx.x * 256 + threadIdx.x; i < n; i += gridDim.x * 256)
    w16[i] = __float2half_rn(w[i]);
}

// ---------------------------------------------------------------------------
// MFMA K/V projection: C16[b][p][n] = A16[b][p][:] @ W16[n][:].
__global__ __launch_bounds__(256) void gemm_kv_mfma(
    const __half* __restrict__ A, const __half* __restrict__ W,
    __half* __restrict__ out)
{
  int b = blockIdx.z;
  int wid = threadIdx.x >> 6;
  int lane = threadIdx.x & 63;
  int p0 = blockIdx.x * 128 + (wid >> 1) * 64;
  int n0 = blockIdx.y * 128 + (wid & 1) * 64;
  const __half* Ab = A + (size_t)b * PP * 256;
  int row = lane & 15;
  int kg  = lane >> 4;
  f32x4 acc[4][4] = {};
  for (int k0 = 0; k0 < 256; k0 += 32) {
    half8 af[4], bf[4];
#pragma unroll
    for (int i = 0; i < 4; ++i)
      af[i] = *(const half8*)&Ab[((size_t)(p0 + 16 * i + row)) * 256 + k0 + kg * 8];
#pragma unroll
    for (int j = 0; j < 4; ++j)
      bf[j] = *(const half8*)&W[((size_t)(n0 + 16 * j + row)) * 256 + k0 + kg * 8];
#pragma unroll
    for (int i = 0; i < 4; ++i)
#pragma unroll
      for (int j = 0; j < 4; ++j)
        acc[i][j] = __builtin_amdgcn_mfma_f32_16x16x32_f16(af[i], bf[j], acc[i][j], 0, 0, 0);
  }
#pragma unroll
  for (int i = 0; i < 4; ++i)
#pragma unroll
    for (int j = 0; j < 4; ++j) {
      int nc = n0 + 16 * j + row;
#pragma unroll
      for (int r = 0; r < 4; ++r) {
        int pr = p0 + 16 * i + kg * 4 + r;
        out[((size_t)b * PP + pr) * 256 + nc] = __float2half_rn(acc[i][j][r]);
      }
    }
}

// ---------------------------------------------------------------------------
// Generic row GEMM: C[r,n] = sum_k (A1[r,k] (+A2[r,k])) * W[n,k] (+bias) (+res) (relu?)
__global__ __launch_bounds__(256) void gemm_rows(
    const float* __restrict__ A1, const float* __restrict__ A2,
    const float* __restrict__ W, const float* __restrict__ bias,
    const float* __restrict__ res, float* __restrict__ C,
    int M, int N, int K, int relu)
{
  __shared__ float a_s[16][65];
  __shared__ float w_s[64][17];
  int bm = blockIdx.x * 64;
  int bn = blockIdx.y * 64;
  int t = threadIdx.x;
  int tp = t & 15, to = t >> 4;
  float acc[4][4] = {};
  for (int k0 = 0; k0 < K; k0 += 16) {
    {
      int rl = t >> 2;
      int kq = (t & 3) * 4;
      int r = bm + rl;
      float4 av = make_float4(0.f, 0.f, 0.f, 0.f);
      if (r < M) {
        av = *(const float4*)&A1[(size_t)r * K + k0 + kq];
        if (A2) {
          float4 bv = *(const float4*)&A2[(size_t)r * K + k0 + kq];
          av.x += bv.x; av.y += bv.y; av.z += bv.z; av.w += bv.w;
        }
      }
      a_s[kq + 0][rl] = av.x; a_s[kq + 1][rl] = av.y;
      a_s[kq + 2][rl] = av.z; a_s[kq + 3][rl] = av.w;
    }
    {
      int ol = t >> 2;
      int kq = (t & 3) * 4;
      float4 wv = *(const float4*)&W[(size_t)(bn + ol) * K + k0 + kq];
      w_s[ol][kq + 0] = wv.x; w_s[ol][kq + 1] = wv.y;
      w_s[ol][kq + 2] = wv.z; w_s[ol][kq + 3] = wv.w;
    }
    __syncthreads();
#pragma unroll
    for (int d = 0; d < 16; ++d) {
      float a[4], w[4];
#pragma unroll
      for (int i = 0; i < 4; ++i) a[i] = a_s[d][tp * 4 + i];
#pragma unroll
      for (int j = 0; j < 4; ++j) w[j] = w_s[to * 4 + j][d];
#pragma unroll
      for (int i = 0; i < 4; ++i)
#pragma unroll
        for (int j = 0; j < 4; ++j)
          acc[i][j] = fmaf(a[i], w[j], acc[i][j]);
    }
    __syncthreads();
  }
#pragma unroll
  for (int i = 0; i < 4; ++i) {
    int r = bm + tp * 4 + i;
    if (r >= M) continue;
#pragma unroll
    for (int j = 0; j < 4; ++j) {
      int n = bn + to * 4 + j;
      float v = acc[i][j];
      if (bias) v += bias[n];
      if (relu) v = fmaxf(v, 0.f);
      if (res)  v += res[(size_t)r * N + n];
      C[(size_t)r * N + n] = v;
    }
  }
}

// ---------------------------------------------------------------------------
// Self-attention, all-heads-batched. One block (8 waves) per (b,q). fp32 K/V.
__global__ __launch_bounds__(512) void sa_attn(
    const float* __restrict__ qkbuf, const float* __restrict__ vbuf,
    float* __restrict__ out)
{
  __shared__ float wmS[8][8];
  __shared__ float wsS[8][8];
  __shared__ float4 ooS[8][64];

  int bid = blockIdx.x;           // b*NQQ + q
  int b = bid / NQQ;
  int wv = threadIdx.x >> 6;
  int lane = threadIdx.x & 63;
  const float scale = 0.17677669529663687f;  // 32^-0.5

  float4 q4 = ((const float4*)(qkbuf + (size_t)bid * 512))[lane];
  q4.x *= scale; q4.y *= scale; q4.z *= scale; q4.w *= scale;

  const float* Kb = qkbuf + (size_t)b * NQQ * 512 + 256;  // k part of rows
  const float* Vb = vbuf + (size_t)b * NQQ * 256;

  float m = -INFINITY, s = 0.f;
  float4 o4 = make_float4(0.f, 0.f, 0.f, 0.f);

  for (int k0 = wv * 8; k0 < NQQ; k0 += 64) {
    const float4* kp = (const float4*)(Kb + (size_t)k0 * 512) + lane;
    const float4* vp = (const float4*)(Vb + (size_t)k0 * 256) + lane;
    float4 kk[8];
#pragma unroll
    for (int i = 0; i < 8; ++i) kk[i] = kp[i * 128];
    float lg[8];
#pragma unroll
    for (int i = 0; i < 8; ++i) {
      float d = q4.x * kk[i].x;
      d = fmaf(q4.y, kk[i].y, d);
      d = fmaf(q4.z, kk[i].z, d);
      d = fmaf(q4.w, kk[i].w, d);
      d += __shfl_xor(d, 1, 64);
      d += __shfl_xor(d, 2, 64);
      d += __shfl_xor(d, 4, 64);
      lg[i] = (k0 + i < NQQ) ? d : -INFINITY;
    }
    float4 vv[8];
#pragma unroll
    for (int i = 0; i < 8; ++i) vv[i] = vp[i * 64];

    float bm = fmaxf(fmaxf(fmaxf(lg[0], lg[1]), fmaxf(lg[2], lg[3])),
                     fmaxf(fmaxf(lg[4], lg[5]), fmaxf(lg[6], lg[7])));
    float mn = fmaxf(m, bm);
    float f = __expf(m - mn);        // first batch: m=-inf -> f=0
    s *= f; o4.x *= f; o4.y *= f; o4.z *= f; o4.w *= f;
    m = mn;
#pragma unroll
    for (int i = 0; i < 8; ++i) {
      float p = __expf(lg[i] - mn);  // tail lg=-inf -> 0
      s += p;
      o4.x = fmaf(p, vv[i].x, o4.x);
      o4.y = fmaf(p, vv[i].y, o4.y);
      o4.z = fmaf(p, vv[i].z, o4.z);
      o4.w = fmaf(p, vv[i].w, o4.w);
    }
  }

  // ---- merge 8 wave-states (per head) ----
  int hg = lane >> 3, sub = lane & 7;
  if (sub == 0) wmS[wv][hg] = m;
  __syncthreads();
  float M = wmS[0][hg];
#pragma unroll
  for (int w = 1; w < 8; ++w) M = fmaxf(M, wmS[w][hg]);
  float f = __expf(m - M);
  if (sub == 0) wsS[wv][hg] = s * f;
  ooS[wv][lane] = make_float4(o4.x * f, o4.y * f, o4.z * f, o4.w * f);
  __syncthreads();
  if (threadIdx.x < 64) {
    int l = threadIdx.x;
    int hg2 = l >> 3;
    float4 acc = make_float4(0.f, 0.f, 0.f, 0.f);
    float den = 0.f;
#pragma unroll
    for (int w = 0; w < 8; ++w) {
      float4 t = ooS[w][l];
      acc.x += t.x; acc.y += t.y; acc.z += t.z; acc.w += t.w;
      den += wsS[w][hg2];
    }
    float inv = 1.f / den;
    float4 res = make_float4(acc.x * inv, acc.y * inv, acc.z * inv, acc.w * inv);
    *(float4*)&out[(size_t)bid * 256 + l * 4] = res;
  }
}

// ---------------------------------------------------------------------------
// Cross-attention partial, fp16 K/V, (key,head)-per-lane QK.
// QK: lane l = key (l>>3), head (l&7); full 32-dim dot lane-local (16 fdot2,
// no shfl). Batch-max = 3 shfl_xor per BATCH. p broadcast to dim-layout PV
// lanes via 8 bpermute. Defer-max (TH=8): rescale only when batch max exceeds
// m+8 (rare). NSPL blocks per (b,q); XCD-grouping swizzle retained.
__global__ __launch_bounds__(512) void ca_attn_part(
    const float* __restrict__ qbuf, const __half* __restrict__ Kbuf,
    const __half* __restrict__ Vbuf, const int* __restrict__ lohi,
    float* __restrict__ pm, float* __restrict__ ps, float* __restrict__ po)
{
  __shared__ float wmS[8][8];
  __shared__ float wsS[8][8];
  __shared__ float4 ooS[8][64];

  // --- swizzle: 4320 blocks = 8 cls x 5 gsub x 27 iq x 4 part ---
  int idx  = blockIdx.x;
  int cls  = idx & 7;
  int rest = idx >> 3;          // 0..539
  int gsub = rest / 108;        // 0..4
  int rem  = rest % 108;
  int iq   = rem >> 2;          // 0..26
  int part = rem & 3;           // NSPL == 4
  int g    = gsub * 8 + cls;    // organ-group 0..39
  int b    = g / 20;
  int q    = (g % 20) * QPO_ + iq;
  int bid  = b * NQQ + q;

  int wv = threadIdx.x >> 6;
  int lane = threadIdx.x & 63;
  int i_k = lane >> 3;          // key slot (key-major: lane = i*8 + h)
  int h_k = lane & 7;           // QK head
  int hg  = lane >> 3;          // PV head (dim layout: lane owns dims 4l..4l+3)
  const float scale = 0.17677669529663687f;

  const int* lh = lohi + (size_t)bid * 6;
  int lo0 = lh[0], lo1 = lh[1], lo2 = lh[2];
  int nx = lh[3] - lo0, ny = lh[4] - lo1, nz = lh[5] - lo2;
  int nxy = nx * ny;
  float inv_ny = 1.0f / (float)ny;

  // q for QK head h_k: 32 dims -> 16 h2v, pre-scaled
  h2v qh[16];
  {
    const float4* qp = (const float4*)(qbuf + (size_t)bid * 256 + h_k * 32);
#pragma unroll
    for (int u = 0; u < 8; ++u) {
      float4 t4 = qp[u];
      qh[2 * u][0]     = (_Float16)(t4.x * scale);
      qh[2 * u][1]     = (_Float16)(t4.y * scale);
      qh[2 * u + 1][0] = (_Float16)(t4.z * scale);
      qh[2 * u + 1][1] = (_Float16)(t4.w * scale);
    }
  }

  const __half* Kb = Kbuf + (size_t)b * PP * 256;
  const __half* Vb = Vbuf + (size_t)b * PP * 256;

  float m_kh = -INFINITY;       // per (lane) = per QK head, softmax ref
  float m_dim = -INFINITY;      // per PV head (same value sequence)
  float s = 0.f;                // partial sum over this lane's keys
  float4 o4 = make_float4(0.f, 0.f, 0.f, 0.f);

#define H2OF(v,j) __builtin_shufflevector(v, v, 2*(j), 2*(j)+1)

  for (int r = part + NSPL * wv; r < nxy; r += NSPL * 8) {
    int x = (int)((float)r * inv_ny);
    int y = r - x * ny;
    if (y < 0)        { x--; y += ny; }
    else if (y >= ny) { x++; y -= ny; }
    int base = (lo0 + x) * (PS1 * PS2) + (lo1 + y) * PS2 + lo2;

    for (int z0 = 0; z0 < nz; z0 += 8) {
      // K: this lane's (key,head) row chunk, 64B = 4 x half8 (over-read ok)
      const half8* kp8 = (const half8*)(Kb + ((size_t)base + z0 + i_k) * 256 + h_k * 32);
      half8 k0 = kp8[0], k1 = kp8[1], k2 = kp8[2], k3 = kp8[3];
      // V: dim layout (8B per key per lane)
      const uint2* vp = (const uint2*)(Vb + ((size_t)base + z0) * 256) + lane;
      uint2 vw[8];
#pragma unroll
      for (int i = 0; i < 8; ++i) vw[i] = vp[i * 64];

      // lane-local 32-dim dot, two chains
      float d0 = 0.f, d1 = 0.f;
      d0 = __builtin_amdgcn_fdot2(H2OF(k0, 0), qh[0],  d0, false);
      d1 = __builtin_amdgcn_fdot2(H2OF(k0, 1), qh[1],  d1, false);
      d0 = __builtin_amdgcn_fdot2(H2OF(k0, 2), qh[2],  d0, false);
      d1 = __builtin_amdgcn_fdot2(H2OF(k0, 3), qh[3],  d1, false);
      d0 = __builtin_amdgcn_fdot2(H2OF(k1, 0), qh[4],  d0, false);
      d1 = __builtin_amdgcn_fdot2(H2OF(k1, 1), qh[5],  d1, false);
      d0 = __builtin_amdgcn_fdot2(H2OF(k1, 2), qh[6],  d0, false);
      d1 = __builtin_amdgcn_fdot2(H2OF(k1, 3), qh[7],  d1, false);
      d0 = __builtin_amdgcn_fdot2(H2OF(k2, 0), qh[8],  d0, false);
      d1 = __builtin_amdgcn_fdot2(H2OF(k2, 1), qh[9],  d1, false);
      d0 = __builtin_amdgcn_fdot2(H2OF(k2, 2), qh[10], d0, false);
      d1 = __builtin_amdgcn_fdot2(H2OF(k2, 3), qh[11], d1, false);
      d0 = __builtin_amdgcn_fdot2(H2OF(k3, 0), qh[12], d0, false);
      d1 = __builtin_amdgcn_fdot2(H2OF(k3, 1), qh[13], d1, false);
      d0 = __builtin_amdgcn_fdot2(H2OF(k3, 2), qh[14], d0, false);
      d1 = __builtin_amdgcn_fdot2(H2OF(k3, 3), qh[15], d1, false);
      float lg = (z0 + i_k < nz) ? (d0 + d1) : -INFINITY;

      // batch max over the 8 key-lanes of each head (stride 8)
      float bm = lg;
      bm = fmaxf(bm, __shfl_xor(bm, 8, 64));
      bm = fmaxf(bm, __shfl_xor(bm, 16, 64));
      bm = fmaxf(bm, __shfl_xor(bm, 32, 64));
      float bmx = __shfl(bm, hg, 64);   // same head's max for the dim layout

      // defer-max: rescale only when needed (first batch: m=-inf -> fires)
      if (bm > m_kh + 8.f) { s *= __expf(m_kh - bm); m_kh = bm; }
      float p = __expf(lg - m_kh);      // masked lg=-inf -> 0
      s += p;
      if (bmx > m_dim + 8.f) {
        float f = __expf(m_dim - bmx);  // m=-inf first -> 0
        o4.x *= f; o4.y *= f; o4.z *= f; o4.w *= f;
        m_dim = bmx;
      }

      // PV: broadcast p from key-lane (i*8 + hg); coalesced V
#pragma unroll
      for (int i = 0; i < 8; ++i) {
        float pi = __shfl(p, i * 8 + hg, 64);
        float4 vf = h4_to_f4(vw[i]);
        o4.x = fmaf(pi, vf.x, o4.x);
        o4.y = fmaf(pi, vf.y, o4.y);
        o4.z = fmaf(pi, vf.z, o4.z);
        o4.w = fmaf(pi, vf.w, o4.w);
      }
    }
  }
#undef H2OF

  // reduce s over the 8 key-lanes of each head, then fetch for dim layout
  s += __shfl_xor(s, 8, 64);
  s += __shfl_xor(s, 16, 64);
  s += __shfl_xor(s, 32, 64);
  float s_h = __shfl(s, hg, 64);        // s for PV head hg (ref = m_dim)

  // ---- merge this block's 8 wave-states; write partial (M, S, O) ----
  int sub = lane & 7;
  if (sub == 0) wmS[wv][hg] = m_dim;
  __syncthreads();
  float M = wmS[0][hg];
#pragma unroll
  for (int w = 1; w < 8; ++w) M = fmaxf(M, wmS[w][hg]);
  float f = (M == -INFINITY) ? 0.f : __expf(m_dim - M);  // empty part -> zeros
  if (sub == 0) wsS[wv][hg] = s_h * f;
  ooS[wv][lane] = make_float4(o4.x * f, o4.y * f, o4.z * f, o4.w * f);
  __syncthreads();
  if (threadIdx.x < 64) {
    int l = threadIdx.x;
    int hg2 = l >> 3;
    float4 acc = make_float4(0.f, 0.f, 0.f, 0.f);
    float den = 0.f;
#pragma unroll
    for (int w = 0; w < 8; ++w) {
      float4 t = ooS[w][l];
      acc.x += t.x; acc.y += t.y; acc.z += t.z; acc.w += t.w;
      den += wsS[w][hg2];
    }
    float M2 = wmS[0][hg2];
#pragma unroll
    for (int w = 1; w < 8; ++w) M2 = fmaxf(M2, wmS[w][hg2]);
    size_t pb = (size_t)bid * NSPL + part;
    if ((l & 7) == 0) { pm[pb * 8 + hg2] = M2; ps[pb * 8 + hg2] = den; }
    *(float4*)&po[pb * 256 + l * 4] = acc;
  }
}

// ---------------------------------------------------------------------------
// Merge NSPL cross-attn partials per query. One wave per (b,q).
__global__ __launch_bounds__(256) void ca_merge(
    const float* __restrict__ pm, const float* __restrict__ ps,
    const float* __restrict__ po, float* __restrict__ out)
{
  int wv = threadIdx.x >> 6;
  int lane = threadIdx.x & 63;
  int bid = blockIdx.x * 4 + wv;
  int hg = lane >> 3;
  size_t pb = (size_t)bid * NSPL;

  float mp[NSPL], sp[NSPL];
#pragma unroll
  for (int p = 0; p < NSPL; ++p) {
    mp[p] = pm[(pb + p) * 8 + hg];
    sp[p] = ps[(pb + p) * 8 + hg];
  }
  float M = fmaxf(fmaxf(mp[0], mp[1]), fmaxf(mp[2], mp[3]));
  float den = 0.f;
  float4 acc = make_float4(0.f, 0.f, 0.f, 0.f);
#pragma unroll
  for (int p = 0; p < NSPL; ++p) {
    float f = __expf(mp[p] - M);     // empty part m=-inf -> 0
    den = fmaf(f, sp[p], den);
    float4 t = *(const float4*)&po[(pb + p) * 256 + lane * 4];
    acc.x = fmaf(f, t.x, acc.x);
    acc.y = fmaf(f, t.y, acc.y);
    acc.z = fmaf(f, t.z, acc.z);
    acc.w = fmaf(f, t.w, acc.w);
  }
  float inv = 1.f / den;
  float4 res = make_float4(acc.x * inv, acc.y * inv, acc.z * inv, acc.w * inv);
  *(float4*)&out[(size_t)bid * 256 + lane * 4] = res;
}

// ---------------------------------------------------------------------------
// LayerNorm over D=256: one wave per row. x already contains residual sum.
__global__ __launch_bounds__(256) void ln_kernel(
    const float* __restrict__ x, const float* __restrict__ g,
    const float* __restrict__ bta, float* __restrict__ out)
{
  int wv = threadIdx.x >> 6;
  int lane = threadIdx.x & 63;
  int row = blockIdx.x * 4 + wv;
  const float* xr = x + (size_t)row * 256;
  float v[4];
#pragma unroll
  for (int j = 0; j < 4; ++j) v[j] = xr[lane + 64 * j];
  float s = v[0] + v[1] + v[2] + v[3];
  s = wred_sum(s);
  float mean = s * (1.f / 256.f);
  float vs = 0.f;
#pragma unroll
  for (int j = 0; j < 4; ++j) { float d = v[j] - mean; vs = fmaf(d, d, vs); }
  vs = wred_sum(vs);
  float inv = rsqrtf(vs * (1.f / 256.f) + 1e-5f);
  float* orow = out + (size_t)row * 256;
#pragma unroll
  for (int j = 0; j < 4; ++j) {
    int c = lane + 64 * j;
    orow[c] = (v[j] - mean) * inv * g[c] + bta[c];
  }
}

// ---------------------------------------------------------------------------
// Layer-0 mask boxes from attn_area.
__global__ __launch_bounds__(256) void mask0_kernel(
    const float* __restrict__ area, int* __restrict__ lohi,
    float px, float py, float pz)
{
  int row = blockIdx.x * 256 + threadIdx.x;
  if (row >= MR) return;
  int q = row % NQQ;
  int org = q / QPO_;
  const float* a = area + org * 6;
  int* o = lohi + (size_t)row * 6;
  o[0] = (int)fminf(fmaxf(floorf(a[0] * 20.f - px), 0.f), 20.f);
  o[1] = (int)fminf(fmaxf(floorf(a[1] * 20.f - py), 0.f), 20.f);
  o[2] = (int)fminf(fmaxf(floorf(a[2] * 32.f - pz), 0.f), 32.f);
  o[3] = (int)fminf(fmaxf(floorf(a[3] * 20.f + px), 0.f), 20.f);
  o[4] = (int)fminf(fmaxf(floorf(a[4] * 20.f + py), 0.f), 20.f);
  o[5] = (int)fminf(fmaxf(floorf(a[5] * 32.f + pz), 0.f), 32.f);
}

// ---------------------------------------------------------------------------
// Layers >=1: prop = h2 @ w3.T + b3 -> tanh*0.1 + anchors -> clip -> box ints.
__global__ __launch_bounds__(256) void mask_reg_kernel(
    const float* __restrict__ h2, const float* __restrict__ w3,
    const float* __restrict__ b3, const float* __restrict__ anchors,
    int* __restrict__ lohi, float px, float py, float pz)
{
  int wv = threadIdx.x >> 6;
  int lane = threadIdx.x & 63;
  int row = blockIdx.x * 4 + wv;
  int q = row % NQQ;
  const float* hr = h2 + (size_t)row * 256;
  float part[6] = {};
#pragma unroll
  for (int j = 0; j < 4; ++j) {
    float hv = hr[lane + 64 * j];
#pragma unroll
    for (int o = 0; o < 6; ++o)
      part[o] = fmaf(hv, w3[o * 256 + lane + 64 * j], part[o]);
  }
#pragma unroll
  for (int o = 0; o < 6; ++o) part[o] = wred_sum(part[o]);
  if (lane == 0) {
    float prop[6];
#pragma unroll
    for (int o = 0; o < 6; ++o) {
      float v = tanhf(part[o] + b3[o]) * 0.1f + anchors[q * 6 + o];
      prop[o] = fminf(fmaxf(v, 0.f), 1.f);
    }
    float vl0 = prop[0] - 0.5f * prop[3], vh0 = prop[0] + 0.5f * prop[3];
    float vl1 = prop[1] - 0.5f * prop[4], vh1 = prop[1] + 0.5f * prop[4];
    float vl2 = prop[2] - 0.5f * prop[5], vh2 = prop[2] + 0.5f * prop[5];
    int* o = lohi + (size_t)row * 6;
    o[0] = (int)fminf(fmaxf(floorf(vl0 * 20.f - px), 0.f), 20.f);
    o[1] = (int)fminf(fmaxf(floorf(vl1 * 20.f - py), 0.f), 20.f);
    o[2] = (int)fminf(fmaxf(floorf(vl2 * 32.f - pz), 0.f), 32.f);
    o[3] = (int)fminf(fmaxf(floorf(vh0 * 20.f + px), 0.f), 20.f);
    o[4] = (int)fminf(fmaxf(floorf(vh1 * 20.f + py), 0.f), 20.f);
    o[5] = (int)fminf(fmaxf(floorf(vh2 * 32.f + pz), 0.f), 32.f);
  }
}

// ---------------------------------------------------------------------------
extern "C" void kernel_launch(void* const* d_in, const int* in_sizes, int n_in,
                              void* d_out, int out_size, void* d_ws, size_t ws_size,
                              hipStream_t stream)
{
  const float* src       = (const float*)d_in[0];
  const float* pos       = (const float*)d_in[1];
  const float* qe        = (const float*)d_in[2];
  const float* sa_in_w   = (const float*)d_in[3];
  const float* sa_in_b   = (const float*)d_in[4];
  const float* sa_out_w  = (const float*)d_in[5];
  const float* sa_out_b  = (const float*)d_in[6];
  const float* ca_k_w    = (const float*)d_in[7];
  const float* ca_v_w    = (const float*)d_in[8];
  const float* ca_proj_w = (const float*)d_in[9];
  const float* ca_proj_b = (const float*)d_in[10];
  const float* ln1_g = (const float*)d_in[11];
  const float* ln1_b = (const float*)d_in[12];
  const float* ln2_g = (const float*)d_in[13];
  const float* ln2_b = (const float*)d_in[14];
  const float* ln3_g = (const float*)d_in[15];
  const float* ln3_b = (const float*)d_in[16];
  const float* ffn_w1 = (const float*)d_in[17];
  const float* ffn_b1 = (const float*)d_in[18];
  const float* ffn_w2 = (const float*)d_in[19];
  const float* ffn_b2 = (const float*)d_in[20];
  const float* reg_w1 = (const float*)d_in[21];
  const float* reg_b1 = (const float*)d_in[22];
  const float* reg_w2 = (const float*)d_in[23];
  const float* reg_b2 = (const float*)d_in[24];
  const float* reg_w3 = (const float*)d_in[25];
  const float* reg_b3 = (const float*)d_in[26];
  const float* anchors   = (const float*)d_in[27];
  const float* attn_area = (const float*)d_in[28];
  float* outp = (float*)d_out;

  float* ws = (float*)d_ws;
  size_t off = 0;
  auto alloc = [&](size_t n) { float* p = ws + off; off += n; return p; };
  __half* Kb = (__half*)alloc((size_t)BB * PP * 128);   // fp16 [b][p][256], 13.1 MB
  __half* Vb = (__half*)alloc((size_t)BB * PP * 128);   // fp16, 13.1 MB
  alloc(2048);                                          // over-read pad
  __half* s16  = (__half*)alloc((size_t)BB * PP * 128); // fp16(src) [b][p][d]
  __half* kv16 = (__half*)alloc((size_t)BB * PP * 128); // fp16(src+pos) [b][p][d]
  __half* kw16 = (__half*)alloc((size_t)LL * DD * DD / 2);
  __half* vw16 = (__half*)alloc((size_t)LL * DD * DD / 2);
  float* tgt  = alloc((size_t)MR * DD);
  float* qpos = alloc((size_t)MR * DD);
  float* tmp  = alloc((size_t)MR * DD);
  float* saqk = alloc((size_t)MR * 512);
  float* sav  = alloc((size_t)MR * DD);
  float* sao  = alloc((size_t)MR * DD);
  float* caq  = alloc((size_t)MR * DD);
  float* cao  = alloc((size_t)MR * DD);
  float* mh1  = alloc((size_t)MR * DD);
  float* mh2  = alloc((size_t)MR * DD);
  float* ffh  = alloc((size_t)MR * FFD);
  float* pmb  = alloc((size_t)MR * NSPL * 8);
  float* psb  = alloc((size_t)MR * NSPL * 8);
  float* pob  = alloc((size_t)MR * NSPL * 256);
  int*   lohi = (int*)alloc((size_t)MR * 6);
  (void)in_sizes; (void)n_in; (void)out_size; (void)ws_size;

  const float FOCUS_H[6] = {0.1f, 0.075f, 0.05f, 0.05f, 0.025f, 0.025f};

  init_kernel<<<1080, 256, 0, stream>>>(qe, tgt, qpos);
  conv_kv_inputs<<<dim3(200, 4, 2), 256, 0, stream>>>(src, pos, s16, kv16);
  conv_w<<<768, 256, 0, stream>>>(ca_k_w, kw16, LL * DD * DD);
  conv_w<<<768, 256, 0, stream>>>(ca_v_w, vw16, LL * DD * DD);

  for (int i = 0; i < LL; ++i) {
    const float* wi  = sa_in_w + (size_t)i * 768 * DD;
    const float* bi  = sa_in_b + (size_t)i * 768;
    // SA: q,k from (tgt+qpos), v from tgt
    gemm_rows<<<dim3(17, 8), 256, 0, stream>>>(tgt, qpos, wi, bi, nullptr, saqk, MR, 512, DD, 0);
    gemm_rows<<<dim3(17, 4), 256, 0, stream>>>(tgt, nullptr, wi + 512 * DD, bi + 512, nullptr, sav, MR, DD, DD, 0);
    sa_attn<<<MR, 512, 0, stream>>>(saqk, sav, sao);
    gemm_rows<<<dim3(17, 4), 256, 0, stream>>>(sao, nullptr, sa_out_w + (size_t)i * DD * DD,
                                               sa_out_b + (size_t)i * DD, tgt, tmp, MR, DD, DD, 0);
    ln_kernel<<<270, 256, 0, stream>>>(tmp, ln2_g + i * DD, ln2_b + i * DD, tgt);

    // mask boxes
    if (i == 0) {
      mask0_kernel<<<5, 256, 0, stream>>>(attn_area, lohi,
          FOCUS_H[0] * PS0, FOCUS_H[0] * PS1, FOCUS_H[0] * PS2);
    } else {
      gemm_rows<<<dim3(17, 4), 256, 0, stream>>>(tgt, nullptr, reg_w1, reg_b1, nullptr, mh1, MR, DD, DD, 1);
      gemm_rows<<<dim3(17, 4), 256, 0, stream>>>(mh1, nullptr, reg_w2, reg_b2, nullptr, mh2, MR, DD, DD, 1);
      mask_reg_kernel<<<270, 256, 0, stream>>>(mh2, reg_w3, reg_b3, anchors, lohi,
          FOCUS_H[i] * PS0, FOCUS_H[i] * PS1, FOCUS_H[i] * PS2);
    }

    // CA: q from (tgt+qpos)@ca_k_w; K from (src+pos)@ca_k_w; V from src@ca_v_w
    gemm_rows<<<dim3(17, 4), 256, 0, stream>>>(tgt, qpos, ca_k_w + (size_t)i * DD * DD,
                                               nullptr, nullptr, caq, MR, DD, DD, 0);
    gemm_kv_mfma<<<dim3(100, 2, 2), 256, 0, stream>>>(kv16, kw16 + (size_t)i * DD * DD, Kb);
    gemm_kv_mfma<<<dim3(100, 2, 2), 256, 0, stream>>>(s16,  vw16 + (size_t)i * DD * DD, Vb);
    ca_attn_part<<<MR * NSPL, 512, 0, stream>>>(caq, Kb, Vb, lohi, pmb, psb, pob);
    ca_merge<<<270, 256, 0, stream>>>(pmb, psb, pob, cao);
    gemm_rows<<<dim3(17, 4), 256, 0, stream>>>(cao, nullptr, ca_proj_w + (size_t)i * DD * DD,
                                               ca_proj_b + (size_t)i * DD, tgt, tmp, MR, DD, DD, 0);
    ln_kernel<<<270, 256, 0, stream>>>(tmp, ln1_g + i * DD, ln1_b + i * DD, tgt);

    // FFN
    gemm_rows<<<dim3(17, 16), 256, 0, stream>>>(tgt, nullptr, ffn_w1 + (size_t)i * FFD * DD,
                                                ffn_b1 + (size_t)i * FFD, nullptr, ffh, MR, FFD, DD, 1);
    gemm_rows<<<dim3(17, 4), 256, 0, stream>>>(ffh, nullptr, ffn_w2 + (size_t)i * DD * FFD,
                                               ffn_b2 + (size_t)i * DD, tgt, tmp, MR, DD, FFD, 0);
    float* lno = (i == LL - 1) ? outp : tgt;
    ln_kernel<<<270, 256, 0, stream>>>(tmp, ln3_g + i * DD, ln3_b + i * DD, lno);
  }
}

// Round 12
// 1871.329 us; speedup vs baseline: 1.5027x; 1.5027x over previous
//
#include <hip/hip_runtime.h>
#include <hip/hip_fp16.h>
#include <math.h>

#define BB 2
#define DD 256
#define HH 8
#define HDIM 32
#define FFD 1024
#define LL 6
#define NQQ 540
#define QPO_ 27
#define PS0 20
#define PS1 20
#define PS2 32
#define PP (PS0*PS1*PS2)   // 12800
#define MR (BB*NQQ)        // 1080
#define NSPL 4             // cross-attn row-partials per query

typedef _Float16 half8 __attribute__((ext_vector_type(8)));
typedef _Float16 h2v  __attribute__((ext_vector_type(2)));
typedef float f32x4 __attribute__((ext_vector_type(4)));

static __device__ __forceinline__ float wred_sum(float x) {
#pragma unroll
  for (int off = 32; off; off >>= 1) x += __shfl_xor(x, off, 64);
  return x;
}
static __device__ __forceinline__ float wred_max(float x) {
#pragma unroll
  for (int off = 32; off; off >>= 1) x = fmaxf(x, __shfl_xor(x, off, 64));
  return x;
}
static __device__ __forceinline__ float4 h4_to_f4(uint2 u) {
  __half2 h0 = *reinterpret_cast<__half2*>(&u.x);
  __half2 h1 = *reinterpret_cast<__half2*>(&u.y);
  float2 f0 = __half22float2(h0);
  float2 f1 = __half22float2(h1);
  return make_float4(f0.x, f0.y, f1.x, f1.y);
}
static __device__ __forceinline__ float dot4h(uint2 kw, h2v q01, h2v q23) {
  h2v a = *reinterpret_cast<h2v*>(&kw.x);
  h2v b = *reinterpret_cast<h2v*>(&kw.y);
  float d = __builtin_amdgcn_fdot2(a, q01, 0.f, false);
  return __builtin_amdgcn_fdot2(b, q23, d, false);
}

// ---------------------------------------------------------------------------
// init: tgt[b,q,d] = qe[q, 256+d]; qpos[b,q,d] = qe[q, d]
__global__ __launch_bounds__(256) void init_kernel(
    const float* __restrict__ qe, float* __restrict__ tgt, float* __restrict__ qpos)
{
  int idx = blockIdx.x * 256 + threadIdx.x;   // < B*NQ*D == 276480
  int d = idx % DD;
  int q = (idx / DD) % NQQ;
  qpos[idx] = qe[q * 512 + d];
  tgt[idx]  = qe[q * 512 + 256 + d];
}

// ---------------------------------------------------------------------------
// One-time: transpose+convert src/pos to fp16 [b][p][d] layouts.
__global__ __launch_bounds__(256) void conv_kv_inputs(
    const float* __restrict__ src, const float* __restrict__ pos,
    __half* __restrict__ s16, __half* __restrict__ kv16)
{
  __shared__ float ls[64][65];
  __shared__ float lk[64][65];
  int b  = blockIdx.z;
  int p0 = blockIdx.x * 64;
  int d0 = blockIdx.y * 64;
  int t = threadIdx.x;
  int pr = (t & 15) * 4;
  int dr = t >> 4;
#pragma unroll
  for (int dd = 0; dd < 64; dd += 16) {
    int d = d0 + dd + dr;
    float4 sv = *(const float4*)&src[((size_t)b * DD + d) * PP + p0 + pr];
    float4 pv = *(const float4*)&pos[((size_t)b * DD + d) * PP + p0 + pr];
    ls[pr + 0][dd + dr] = sv.x; ls[pr + 1][dd + dr] = sv.y;
    ls[pr + 2][dd + dr] = sv.z; ls[pr + 3][dd + dr] = sv.w;
    lk[pr + 0][dd + dr] = sv.x + pv.x; lk[pr + 1][dd + dr] = sv.y + pv.y;
    lk[pr + 2][dd + dr] = sv.z + pv.z; lk[pr + 3][dd + dr] = sv.w + pv.w;
  }
  __syncthreads();
  int wp = t >> 2;
  int wd = (t & 3) * 16;
  size_t base = ((size_t)b * PP + p0 + wp) * 256 + d0 + wd;
#pragma unroll
  for (int i = 0; i < 16; i += 2) {
    *(__half2*)&s16[base + i]  = __floats2half2_rn(ls[wp][wd + i], ls[wp][wd + i + 1]);
    *(__half2*)&kv16[base + i] = __floats2half2_rn(lk[wp][wd + i], lk[wp][wd + i + 1]);
  }
}

// One-time: fp32 -> fp16 weight conversion (grid-stride).
__global__ __launch_bounds__(256) void conv_w(
    const float* __restrict__ w, __half* __restrict__ w16, int n)
{
  for (int i = blockIdx.x * 256 + threadIdx.x; i < n; i += gridDim.x * 256)
    w16[i] = __float2half_rn(w[i]);
}

// ---------------------------------------------------------------------------
// MFMA K/V projection: C16[b][p][n] = A16[b][p][:] @ W16[n][:].
__global__ __launch_bounds__(256) void gemm_kv_mfma(
    const __half* __restrict__ A, const __half* __restrict__ W,
    __half* __restrict__ out)
{
  int b = blockIdx.z;
  int wid = threadIdx.x >> 6;
  int lane = threadIdx.x & 63;
  int p0 = blockIdx.x * 128 + (wid >> 1) * 64;
  int n0 = blockIdx.y * 128 + (wid & 1) * 64;
  const __half* Ab = A + (size_t)b * PP * 256;
  int row = lane & 15;
  int kg  = lane >> 4;
  f32x4 acc[4][4] = {};
  for (int k0 = 0; k0 < 256; k0 += 32) {
    half8 af[4], bf[4];
#pragma unroll
    for (int i = 0; i < 4; ++i)
      af[i] = *(const half8*)&Ab[((size_t)(p0 + 16 * i + row)) * 256 + k0 + kg * 8];
#pragma unroll
    for (int j = 0; j < 4; ++j)
      bf[j] = *(const half8*)&W[((size_t)(n0 + 16 * j + row)) * 256 + k0 + kg * 8];
#pragma unroll
    for (int i = 0; i < 4; ++i)
#pragma unroll
      for (int j = 0; j < 4; ++j)
        acc[i][j] = __builtin_amdgcn_mfma_f32_16x16x32_f16(af[i], bf[j], acc[i][j], 0, 0, 0);
  }
#pragma unroll
  for (int i = 0; i < 4; ++i)
#pragma unroll
    for (int j = 0; j < 4; ++j) {
      int nc = n0 + 16 * j + row;
#pragma unroll
      for (int r = 0; r < 4; ++r) {
        int pr = p0 + 16 * i + kg * 4 + r;
        out[((size_t)b * PP + pr) * 256 + nc] = __float2half_rn(acc[i][j][r]);
      }
    }
}

// ---------------------------------------------------------------------------
// MFMA row GEMM: C[r,n] = (A1[r,:](+A2[r,:])) @ W16[n,:] (+bias)(+res)(relu).
// fp32 A staged per-K-step into LDS as fp16 (64x32 tile); W16 pre-converted.
// Block 256 thr = 4 waves; tile 64M x 64N; wave w owns N-strip w*16.
// Fragment mapping identical to gemm_kv_mfma (verified end-to-end).
__global__ __launch_bounds__(256) void gemm_rows_mfma(
    const float* __restrict__ A1, const float* __restrict__ A2,
    const __half* __restrict__ W, const float* __restrict__ bias,
    const float* __restrict__ res, float* __restrict__ C,
    int M, int N, int K, int relu)
{
  __shared__ __half a_s[64][40];   // row stride 80B (16B-mult): aligned half8 ops
  int bm = blockIdx.x * 64;
  int bn = blockIdx.y * 64;
  int wv = threadIdx.x >> 6;
  int lane = threadIdx.x & 63;
  int row = lane & 15;
  int kg  = lane >> 4;
  int nw  = bn + wv * 16;
  int t = threadIdx.x;
  int srow = t >> 2, skq = (t & 3) * 8;
  f32x4 acc[4] = {};

  for (int k0 = 0; k0 < K; k0 += 32) {
    { // stage A tile (64 rows x 32 k) as fp16; over-read rows land in ws
      size_t off = (size_t)(bm + srow) * K + k0 + skq;
      float4 a0 = *(const float4*)&A1[off];
      float4 a1 = *(const float4*)&A1[off + 4];
      if (A2) {
        float4 b0 = *(const float4*)&A2[off];
        float4 b1 = *(const float4*)&A2[off + 4];
        a0.x += b0.x; a0.y += b0.y; a0.z += b0.z; a0.w += b0.w;
        a1.x += b1.x; a1.y += b1.y; a1.z += b1.z; a1.w += b1.w;
      }
      half8 h;
      h[0] = (_Float16)a0.x; h[1] = (_Float16)a0.y;
      h[2] = (_Float16)a0.z; h[3] = (_Float16)a0.w;
      h[4] = (_Float16)a1.x; h[5] = (_Float16)a1.y;
      h[6] = (_Float16)a1.z; h[7] = (_Float16)a1.w;
      *(half8*)&a_s[srow][skq] = h;
    }
    __syncthreads();
    half8 bf = *(const half8*)&W[(size_t)(nw + row) * K + k0 + kg * 8];
#pragma unroll
    for (int i = 0; i < 4; ++i) {
      half8 af = *(const half8*)&a_s[16 * i + row][kg * 8];
      acc[i] = __builtin_amdgcn_mfma_f32_16x16x32_f16(af, bf, acc[i], 0, 0, 0);
    }
    __syncthreads();
  }

  int col = nw + row;
  float bval = bias ? bias[col] : 0.f;
#pragma unroll
  for (int i = 0; i < 4; ++i) {
#pragma unroll
    for (int r = 0; r < 4; ++r) {
      int rr = bm + 16 * i + kg * 4 + r;
      if (rr >= M) continue;
      float v = acc[i][r] + bval;
      if (relu) v = fmaxf(v, 0.f);
      if (res)  v += res[(size_t)rr * N + col];
      C[(size_t)rr * N + col] = v;
    }
  }
}

// ---------------------------------------------------------------------------
// Self-attention, all-heads-batched. One block (8 waves) per (b,q). fp32 K/V.
__global__ __launch_bounds__(512) void sa_attn(
    const float* __restrict__ qkbuf, const float* __restrict__ vbuf,
    float* __restrict__ out)
{
  __shared__ float wmS[8][8];
  __shared__ float wsS[8][8];
  __shared__ float4 ooS[8][64];

  int bid = blockIdx.x;           // b*NQQ + q
  int b = bid / NQQ;
  int wv = threadIdx.x >> 6;
  int lane = threadIdx.x & 63;
  const float scale = 0.17677669529663687f;  // 32^-0.5

  float4 q4 = ((const float4*)(qkbuf + (size_t)bid * 512))[lane];
  q4.x *= scale; q4.y *= scale; q4.z *= scale; q4.w *= scale;

  const float* Kb = qkbuf + (size_t)b * NQQ * 512 + 256;  // k part of rows
  const float* Vb = vbuf + (size_t)b * NQQ * 256;

  float m = -INFINITY, s = 0.f;
  float4 o4 = make_float4(0.f, 0.f, 0.f, 0.f);

  for (int k0 = wv * 8; k0 < NQQ; k0 += 64) {
    const float4* kp = (const float4*)(Kb + (size_t)k0 * 512) + lane;
    const float4* vp = (const float4*)(Vb + (size_t)k0 * 256) + lane;
    float4 kk[8];
#pragma unroll
    for (int i = 0; i < 8; ++i) kk[i] = kp[i * 128];
    float lg[8];
#pragma unroll
    for (int i = 0; i < 8; ++i) {
      float d = q4.x * kk[i].x;
      d = fmaf(q4.y, kk[i].y, d);
      d = fmaf(q4.z, kk[i].z, d);
      d = fmaf(q4.w, kk[i].w, d);
      d += __shfl_xor(d, 1, 64);
      d += __shfl_xor(d, 2, 64);
      d += __shfl_xor(d, 4, 64);
      lg[i] = (k0 + i < NQQ) ? d : -INFINITY;
    }
    float4 vv[8];
#pragma unroll
    for (int i = 0; i < 8; ++i) vv[i] = vp[i * 64];

    float bm = fmaxf(fmaxf(fmaxf(lg[0], lg[1]), fmaxf(lg[2], lg[3])),
                     fmaxf(fmaxf(lg[4], lg[5]), fmaxf(lg[6], lg[7])));
    float mn = fmaxf(m, bm);
    float f = __expf(m - mn);        // first batch: m=-inf -> f=0
    s *= f; o4.x *= f; o4.y *= f; o4.z *= f; o4.w *= f;
    m = mn;
#pragma unroll
    for (int i = 0; i < 8; ++i) {
      float p = __expf(lg[i] - mn);  // tail lg=-inf -> 0
      s += p;
      o4.x = fmaf(p, vv[i].x, o4.x);
      o4.y = fmaf(p, vv[i].y, o4.y);
      o4.z = fmaf(p, vv[i].z, o4.z);
      o4.w = fmaf(p, vv[i].w, o4.w);
    }
  }

  // ---- merge 8 wave-states (per head) ----
  int hg = lane >> 3, sub = lane & 7;
  if (sub == 0) wmS[wv][hg] = m;
  __syncthreads();
  float M = wmS[0][hg];
#pragma unroll
  for (int w = 1; w < 8; ++w) M = fmaxf(M, wmS[w][hg]);
  float f = __expf(m - M);
  if (sub == 0) wsS[wv][hg] = s * f;
  ooS[wv][lane] = make_float4(o4.x * f, o4.y * f, o4.z * f, o4.w * f);
  __syncthreads();
  if (threadIdx.x < 64) {
    int l = threadIdx.x;
    int hg2 = l >> 3;
    float4 acc = make_float4(0.f, 0.f, 0.f, 0.f);
    float den = 0.f;
#pragma unroll
    for (int w = 0; w < 8; ++w) {
      float4 t = ooS[w][l];
      acc.x += t.x; acc.y += t.y; acc.z += t.z; acc.w += t.w;
      den += wsS[w][hg2];
    }
    float inv = 1.f / den;
    float4 res = make_float4(acc.x * inv, acc.y * inv, acc.z * inv, acc.w * inv);
    *(float4*)&out[(size_t)bid * 256 + l * 4] = res;
  }
}

// ---------------------------------------------------------------------------
// Cross-attention partial (R9 version: dim-layout lanes, fdot2 QK, split
// even/odd accumulator chains). fp16 K/V; NSPL blocks per (b,q); XCD swizzle.
__global__ __launch_bounds__(512) void ca_attn_part(
    const float* __restrict__ qbuf, const __half* __restrict__ Kbuf,
    const __half* __restrict__ Vbuf, const int* __restrict__ lohi,
    float* __restrict__ pm, float* __restrict__ ps, float* __restrict__ po)
{
  __shared__ float wmS[8][8];
  __shared__ float wsS[8][8];
  __shared__ float4 ooS[8][64];

  // --- swizzle: 4320 blocks = 8 cls x 5 gsub x 27 iq x 4 part ---
  int idx  = blockIdx.x;
  int cls  = idx & 7;
  int rest = idx >> 3;          // 0..539
  int gsub = rest / 108;        // 0..4
  int rem  = rest % 108;
  int iq   = rem >> 2;          // 0..26
  int part = rem & 3;           // NSPL == 4
  int g    = gsub * 8 + cls;    // organ-group 0..39
  int b    = g / 20;
  int q    = (g % 20) * QPO_ + iq;
  int bid  = b * NQQ + q;

  int wv = threadIdx.x >> 6;
  int lane = threadIdx.x & 63;
  const float scale = 0.17677669529663687f;

  const int* lh = lohi + (size_t)bid * 6;
  int lo0 = lh[0], lo1 = lh[1], lo2 = lh[2];
  int nx = lh[3] - lo0, ny = lh[4] - lo1, nz = lh[5] - lo2;
  int nxy = nx * ny;
  float inv_ny = 1.0f / (float)ny;

  float4 q4 = ((const float4*)(qbuf + (size_t)bid * 256))[lane];
  q4.x *= scale; q4.y *= scale; q4.z *= scale; q4.w *= scale;
  h2v q01, q23;
  q01[0] = (_Float16)q4.x; q01[1] = (_Float16)q4.y;
  q23[0] = (_Float16)q4.z; q23[1] = (_Float16)q4.w;

  const __half* Kb = Kbuf + (size_t)b * PP * 256;
  const __half* Vb = Vbuf + (size_t)b * PP * 256;

  float m = -INFINITY, sA = 0.f, sB = 0.f;
  float4 oA = make_float4(0.f, 0.f, 0.f, 0.f);
  float4 oB = make_float4(0.f, 0.f, 0.f, 0.f);

  for (int r = part + NSPL * wv; r < nxy; r += NSPL * 8) {
    int x = (int)((float)r * inv_ny);
    int y = r - x * ny;
    if (y < 0)        { x--; y += ny; }
    else if (y >= ny) { x++; y -= ny; }
    int base = (lo0 + x) * (PS1 * PS2) + (lo1 + y) * PS2 + lo2;

    for (int z0 = 0; z0 < nz; z0 += 8) {
      const uint2* kp = (const uint2*)(Kb + ((size_t)base + z0) * 256) + lane;
      const uint2* vp = (const uint2*)(Vb + ((size_t)base + z0) * 256) + lane;
      uint2 kw[8];
#pragma unroll
      for (int i = 0; i < 8; ++i) kw[i] = kp[i * 64];   // row stride 256 halfs
      uint2 vw[8];
#pragma unroll
      for (int i = 0; i < 8; ++i) vw[i] = vp[i * 64];

      float lg[8];
#pragma unroll
      for (int i = 0; i < 8; ++i) {
        float d = dot4h(kw[i], q01, q23);
        d += __shfl_xor(d, 1, 64);
        d += __shfl_xor(d, 2, 64);
        d += __shfl_xor(d, 4, 64);
        lg[i] = (z0 + i < nz) ? d : -INFINITY;
      }

      float bm = fmaxf(fmaxf(fmaxf(lg[0], lg[1]), fmaxf(lg[2], lg[3])),
                       fmaxf(fmaxf(lg[4], lg[5]), fmaxf(lg[6], lg[7])));
      float mn = fmaxf(m, bm);
      float f = __expf(m - mn);      // first batch: m=-inf -> f=0
      sA *= f; sB *= f;
      oA.x *= f; oA.y *= f; oA.z *= f; oA.w *= f;
      oB.x *= f; oB.y *= f; oB.z *= f; oB.w *= f;
      m = mn;
#pragma unroll
      for (int i = 0; i < 8; i += 2) {
        float pa = __expf(lg[i] - mn);      // masked -inf -> 0
        float pb = __expf(lg[i + 1] - mn);
        float4 va = h4_to_f4(vw[i]);
        float4 vb = h4_to_f4(vw[i + 1]);
        sA += pa; sB += pb;
        oA.x = fmaf(pa, va.x, oA.x); oB.x = fmaf(pb, vb.x, oB.x);
        oA.y = fmaf(pa, va.y, oA.y); oB.y = fmaf(pb, vb.y, oB.y);
        oA.z = fmaf(pa, va.z, oA.z); oB.z = fmaf(pb, vb.z, oB.z);
        oA.w = fmaf(pa, va.w, oA.w); oB.w = fmaf(pb, vb.w, oB.w);
      }
    }
  }

  float s = sA + sB;
  float4 o4 = make_float4(oA.x + oB.x, oA.y + oB.y, oA.z + oB.z, oA.w + oB.w);

  // ---- merge this block's 8 wave-states; write partial (M, S, O) ----
  int hg = lane >> 3, sub = lane & 7;
  if (sub == 0) wmS[wv][hg] = m;
  __syncthreads();
  float M = wmS[0][hg];
#pragma unroll
  for (int w = 1; w < 8; ++w) M = fmaxf(M, wmS[w][hg]);
  float f = (M == -INFINITY) ? 0.f : __expf(m - M);  // empty part -> zeros
  if (sub == 0) wsS[wv][hg] = s * f;
  ooS[wv][lane] = make_float4(o4.x * f, o4.y * f, o4.z * f, o4.w * f);
  __syncthreads();
  if (threadIdx.x < 64) {
    int l = threadIdx.x;
    int hg2 = l >> 3;
    float4 acc = make_float4(0.f, 0.f, 0.f, 0.f);
    float den = 0.f;
#pragma unroll
    for (int w = 0; w < 8; ++w) {
      float4 t = ooS[w][l];
      acc.x += t.x; acc.y += t.y; acc.z += t.z; acc.w += t.w;
      den += wsS[w][hg2];
    }
    float M2 = wmS[0][hg2];
#pragma unroll
    for (int w = 1; w < 8; ++w) M2 = fmaxf(M2, wmS[w][hg2]);
    size_t pb = (size_t)bid * NSPL + part;
    if ((l & 7) == 0) { pm[pb * 8 + hg2] = M2; ps[pb * 8 + hg2] = den; }
    *(float4*)&po[pb * 256 + l * 4] = acc;
  }
}

// ---------------------------------------------------------------------------
// Merge NSPL cross-attn partials per query. One wave per (b,q).
__global__ __launch_bounds__(256) void ca_merge(
    const float* __restrict__ pm, const float* __restrict__ ps,
    const float* __restrict__ po, float* __restrict__ out)
{
  int wv = threadIdx.x >> 6;
  int lane = threadIdx.x & 63;
  int bid = blockIdx.x * 4 + wv;
  int hg = lane >> 3;
  size_t pb = (size_t)bid * NSPL;

  float mp[NSPL], sp[NSPL];
#pragma unroll
  for (int p = 0; p < NSPL; ++p) {
    mp[p] = pm[(pb + p) * 8 + hg];
    sp[p] = ps[(pb + p) * 8 + hg];
  }
  float M = fmaxf(fmaxf(mp[0], mp[1]), fmaxf(mp[2], mp[3]));
  float den = 0.f;
  float4 acc = make_float4(0.f, 0.f, 0.f, 0.f);
#pragma unroll
  for (int p = 0; p < NSPL; ++p) {
    float f = __expf(mp[p] - M);     // empty part m=-inf -> 0
    den = fmaf(f, sp[p], den);
    float4 t = *(const float4*)&po[(pb + p) * 256 + lane * 4];
    acc.x = fmaf(f, t.x, acc.x);
    acc.y = fmaf(f, t.y, acc.y);
    acc.z = fmaf(f, t.z, acc.z);
    acc.w = fmaf(f, t.w, acc.w);
  }
  float inv = 1.f / den;
  float4 res = make_float4(acc.x * inv, acc.y * inv, acc.z * inv, acc.w * inv);
  *(float4*)&out[(size_t)bid * 256 + lane * 4] = res;
}

// ---------------------------------------------------------------------------
// LayerNorm over D=256: one wave per row. x already contains residual sum.
__global__ __launch_bounds__(256) void ln_kernel(
    const float* __restrict__ x, const float* __restrict__ g,
    const float* __restrict__ bta, float* __restrict__ out)
{
  int wv = threadIdx.x >> 6;
  int lane = threadIdx.x & 63;
  int row = blockIdx.x * 4 + wv;
  const float* xr = x + (size_t)row * 256;
  float v[4];
#pragma unroll
  for (int j = 0; j < 4; ++j) v[j] = xr[lane + 64 * j];
  float s = v[0] + v[1] + v[2] + v[3];
  s = wred_sum(s);
  float mean = s * (1.f / 256.f);
  float vs = 0.f;
#pragma unroll
  for (int j = 0; j < 4; ++j) { float d = v[j] - mean; vs = fmaf(d, d, vs); }
  vs = wred_sum(vs);
  float inv = rsqrtf(vs * (1.f / 256.f) + 1e-5f);
  float* orow = out + (size_t)row * 256;
#pragma unroll
  for (int j = 0; j < 4; ++j) {
    int c = lane + 64 * j;
    orow[c] = (v[j] - mean) * inv * g[c] + bta[c];
  }
}

// ---------------------------------------------------------------------------
// Layer-0 mask boxes from attn_area.
__global__ __launch_bounds__(256) void mask0_kernel(
    const float* __restrict__ area, int* __restrict__ lohi,
    float px, float py, float pz)
{
  int row = blockIdx.x * 256 + threadIdx.x;
  if (row >= MR) return;
  int q = row % NQQ;
  int org = q / QPO_;
  const float* a = area + org * 6;
  int* o = lohi + (size_t)row * 6;
  o[0] = (int)fminf(fmaxf(floorf(a[0] * 20.f - px), 0.f), 20.f);
  o[1] = (int)fminf(fmaxf(floorf(a[1] * 20.f - py), 0.f), 20.f);
  o[2] = (int)fminf(fmaxf(floorf(a[2] * 32.f - pz), 0.f), 32.f);
  o[3] = (int)fminf(fmaxf(floorf(a[3] * 20.f + px), 0.f), 20.f);
  o[4] = (int)fminf(fmaxf(floorf(a[4] * 20.f + py), 0.f), 20.f);
  o[5] = (int)fminf(fmaxf(floorf(a[5] * 32.f + pz), 0.f), 32.f);
}

// ---------------------------------------------------------------------------
// Layers >=1: prop = h2 @ w3.T + b3 -> tanh*0.1 + anchors -> clip -> box ints.
__global__ __launch_bounds__(256) void mask_reg_kernel(
    const float* __restrict__ h2, const float* __restrict__ w3,
    const float* __restrict__ b3, const float* __restrict__ anchors,
    int* __restrict__ lohi, float px, float py, float pz)
{
  int wv = threadIdx.x >> 6;
  int lane = threadIdx.x & 63;
  int row = blockIdx.x * 4 + wv;
  int q = row % NQQ;
  const float* hr = h2 + (size_t)row * 256;
  float part[6] = {};
#pragma unroll
  for (int j = 0; j < 4; ++j) {
    float hv = hr[lane + 64 * j];
#pragma unroll
    for (int o = 0; o < 6; ++o)
      part[o] = fmaf(hv, w3[o * 256 + lane + 64 * j], part[o]);
  }
#pragma unroll
  for (int o = 0; o < 6; ++o) part[o] = wred_sum(part[o]);
  if (lane == 0) {
    float prop[6];
#pragma unroll
    for (int o = 0; o < 6; ++o) {
      float v = tanhf(part[o] + b3[o]) * 0.1f + anchors[q * 6 + o];
      prop[o] = fminf(fmaxf(v, 0.f), 1.f);
    }
    float vl0 = prop[0] - 0.5f * prop[3], vh0 = prop[0] + 0.5f * prop[3];
    float vl1 = prop[1] - 0.5f * prop[4], vh1 = prop[1] + 0.5f * prop[4];
    float vl2 = prop[2] - 0.5f * prop[5], vh2 = prop[2] + 0.5f * prop[5];
    int* o = lohi + (size_t)row * 6;
    o[0] = (int)fminf(fmaxf(floorf(vl0 * 20.f - px), 0.f), 20.f);
    o[1] = (int)fminf(fmaxf(floorf(vl1 * 20.f - py), 0.f), 20.f);
    o[2] = (int)fminf(fmaxf(floorf(vl2 * 32.f - pz), 0.f), 32.f);
    o[3] = (int)fminf(fmaxf(floorf(vh0 * 20.f + px), 0.f), 20.f);
    o[4] = (int)fminf(fmaxf(floorf(vh1 * 20.f + py), 0.f), 20.f);
    o[5] = (int)fminf(fmaxf(floorf(vh2 * 32.f + pz), 0.f), 32.f);
  }
}

// ---------------------------------------------------------------------------
extern "C" void kernel_launch(void* const* d_in, const int* in_sizes, int n_in,
                              void* d_out, int out_size, void* d_ws, size_t ws_size,
                              hipStream_t stream)
{
  const float* src       = (const float*)d_in[0];
  const float* pos       = (const float*)d_in[1];
  const float* qe        = (const float*)d_in[2];
  const float* sa_in_w   = (const float*)d_in[3];
  const float* sa_in_b   = (const float*)d_in[4];
  const float* sa_out_w  = (const float*)d_in[5];
  const float* sa_out_b  = (const float*)d_in[6];
  const float* ca_k_w    = (const float*)d_in[7];
  const float* ca_v_w    = (const float*)d_in[8];
  const float* ca_proj_w = (const float*)d_in[9];
  const float* ca_proj_b = (const float*)d_in[10];
  const float* ln1_g = (const float*)d_in[11];
  const float* ln1_b = (const float*)d_in[12];
  const float* ln2_g = (const float*)d_in[13];
  const float* ln2_b = (const float*)d_in[14];
  const float* ln3_g = (const float*)d_in[15];
  const float* ln3_b = (const float*)d_in[16];
  const float* ffn_w1 = (const float*)d_in[17];
  const float* ffn_b1 = (const float*)d_in[18];
  const float* ffn_w2 = (const float*)d_in[19];
  const float* ffn_b2 = (const float*)d_in[20];
  const float* reg_w1 = (const float*)d_in[21];
  const float* reg_b1 = (const float*)d_in[22];
  const float* reg_w2 = (const float*)d_in[23];
  const float* reg_b2 = (const float*)d_in[24];
  const float* reg_w3 = (const float*)d_in[25];
  const float* reg_b3 = (const float*)d_in[26];
  const float* anchors   = (const float*)d_in[27];
  const float* attn_area = (const float*)d_in[28];
  float* outp = (float*)d_out;

  float* ws = (float*)d_ws;
  size_t off = 0;
  auto alloc = [&](size_t n) { float* p = ws + off; off += n; return p; };
  __half* Kb = (__half*)alloc((size_t)BB * PP * 128);   // fp16 [b][p][256], 13.1 MB
  __half* Vb = (__half*)alloc((size_t)BB * PP * 128);   // fp16, 13.1 MB
  alloc(2048);                                          // over-read pad
  __half* s16  = (__half*)alloc((size_t)BB * PP * 128); // fp16(src) [b][p][d]
  __half* kv16 = (__half*)alloc((size_t)BB * PP * 128); // fp16(src+pos) [b][p][d]
  __half* kw16 = (__half*)alloc((size_t)LL * DD * DD / 2);
  __half* vw16 = (__half*)alloc((size_t)LL * DD * DD / 2);
  __half* saw16 = (__half*)alloc((size_t)LL * 768 * DD / 2);   // sa_in_w
  __half* sow16 = (__half*)alloc((size_t)LL * DD * DD / 2);    // sa_out_w
  __half* pw16  = (__half*)alloc((size_t)LL * DD * DD / 2);    // ca_proj_w
  __half* f1w16 = (__half*)alloc((size_t)LL * FFD * DD / 2);   // ffn_w1
  __half* f2w16 = (__half*)alloc((size_t)LL * DD * FFD / 2);   // ffn_w2
  __half* r1w16 = (__half*)alloc((size_t)DD * DD / 2);         // reg_w1
  __half* r2w16 = (__half*)alloc((size_t)DD * DD / 2);         // reg_w2
  float* tgt  = alloc((size_t)MR * DD);
  float* qpos = alloc((size_t)MR * DD);
  float* tmp  = alloc((size_t)MR * DD);
  float* saqk = alloc((size_t)MR * 512);
  float* sav  = alloc((size_t)MR * DD);
  float* sao  = alloc((size_t)MR * DD);
  float* caq  = alloc((size_t)MR * DD);
  float* cao  = alloc((size_t)MR * DD);
  float* mh1  = alloc((size_t)MR * DD);
  float* mh2  = alloc((size_t)MR * DD);
  float* ffh  = alloc((size_t)MR * FFD);
  float* pmb  = alloc((size_t)MR * NSPL * 8);
  float* psb  = alloc((size_t)MR * NSPL * 8);
  float* pob  = alloc((size_t)MR * NSPL * 256);
  int*   lohi = (int*)alloc((size_t)MR * 6);
  alloc(4096);                                          // A over-read pad (after lohi)
  (void)in_sizes; (void)n_in; (void)out_size; (void)ws_size;

  const float FOCUS_H[6] = {0.1f, 0.075f, 0.05f, 0.05f, 0.025f, 0.025f};

  init_kernel<<<1080, 256, 0, stream>>>(qe, tgt, qpos);
  conv_kv_inputs<<<dim3(200, 4, 2), 256, 0, stream>>>(src, pos, s16, kv16);
  conv_w<<<768, 256, 0, stream>>>(ca_k_w, kw16, LL * DD * DD);
  conv_w<<<768, 256, 0, stream>>>(ca_v_w, vw16, LL * DD * DD);
  conv_w<<<768, 256, 0, stream>>>(sa_in_w, saw16, LL * 768 * DD);
  conv_w<<<768, 256, 0, stream>>>(sa_out_w, sow16, LL * DD * DD);
  conv_w<<<768, 256, 0, stream>>>(ca_proj_w, pw16, LL * DD * DD);
  conv_w<<<768, 256, 0, stream>>>(ffn_w1, f1w16, LL * FFD * DD);
  conv_w<<<768, 256, 0, stream>>>(ffn_w2, f2w16, LL * DD * FFD);
  conv_w<<<256, 256, 0, stream>>>(reg_w1, r1w16, DD * DD);
  conv_w<<<256, 256, 0, stream>>>(reg_w2, r2w16, DD * DD);

  for (int i = 0; i < LL; ++i) {
    const __half* wi16 = saw16 + (size_t)i * 768 * DD;
    const float*  bi   = sa_in_b + (size_t)i * 768;
    // SA: q,k from (tgt+qpos), v from tgt
    gemm_rows_mfma<<<dim3(17, 8), 256, 0, stream>>>(tgt, qpos, wi16, bi, nullptr, saqk, MR, 512, DD, 0);
    gemm_rows_mfma<<<dim3(17, 4), 256, 0, stream>>>(tgt, nullptr, wi16 + 512 * DD, bi + 512, nullptr, sav, MR, DD, DD, 0);
    sa_attn<<<MR, 512, 0, stream>>>(saqk, sav, sao);
    gemm_rows_mfma<<<dim3(17, 4), 256, 0, stream>>>(sao, nullptr, sow16 + (size_t)i * DD * DD,
                                                    sa_out_b + (size_t)i * DD, tgt, tmp, MR, DD, DD, 0);
    ln_kernel<<<270, 256, 0, stream>>>(tmp, ln2_g + i * DD, ln2_b + i * DD, tgt);

    // mask boxes
    if (i == 0) {
      mask0_kernel<<<5, 256, 0, stream>>>(attn_area, lohi,
          FOCUS_H[0] * PS0, FOCUS_H[0] * PS1, FOCUS_H[0] * PS2);
    } else {
      gemm_rows_mfma<<<dim3(17, 4), 256, 0, stream>>>(tgt, nullptr, r1w16, reg_b1, nullptr, mh1, MR, DD, DD, 1);
      gemm_rows_mfma<<<dim3(17, 4), 256, 0, stream>>>(mh1, nullptr, r2w16, reg_b2, nullptr, mh2, MR, DD, DD, 1);
      mask_reg_kernel<<<270, 256, 0, stream>>>(mh2, reg_w3, reg_b3, anchors, lohi,
          FOCUS_H[i] * PS0, FOCUS_H[i] * PS1, FOCUS_H[i] * PS2);
    }

    // CA: q from (tgt+qpos)@ca_k_w; K from (src+pos)@ca_k_w; V from src@ca_v_w
    gemm_rows_mfma<<<dim3(17, 4), 256, 0, stream>>>(tgt, qpos, kw16 + (size_t)i * DD * DD,
                                                    nullptr, nullptr, caq, MR, DD, DD, 0);
    gemm_kv_mfma<<<dim3(100, 2, 2), 256, 0, stream>>>(kv16, kw16 + (size_t)i * DD * DD, Kb);
    gemm_kv_mfma<<<dim3(100, 2, 2), 256, 0, stream>>>(s16,  vw16 + (size_t)i * DD * DD, Vb);
    ca_attn_part<<<MR * NSPL, 512, 0, stream>>>(caq, Kb, Vb, lohi, pmb, psb, pob);
    ca_merge<<<270, 256, 0, stream>>>(pmb, psb, pob, cao);
    gemm_rows_mfma<<<dim3(17, 4), 256, 0, stream>>>(cao, nullptr, pw16 + (size_t)i * DD * DD,
                                                    ca_proj_b + (size_t)i * DD, tgt, tmp, MR, DD, DD, 0);
    ln_kernel<<<270, 256, 0, stream>>>(tmp, ln1_g + i * DD, ln1_b + i * DD, tgt);

    // FFN
    gemm_rows_mfma<<<dim3(17, 16), 256, 0, stream>>>(tgt, nullptr, f1w16 + (size_t)i * FFD * DD,
                                                     ffn_b1 + (size_t)i * FFD, nullptr, ffh, MR, FFD, DD, 1);
    gemm_rows_mfma<<<dim3(17, 4), 256, 0, stream>>>(ffh, nullptr, f2w16 + (size_t)i * DD * FFD,
                                                    ffn_b2 + (size_t)i * DD, tgt, tmp, MR, DD, FFD, 0);
    float* lno = (i == LL - 1) ? outp : tgt;
    ln_kernel<<<270, 256, 0, stream>>>(tmp, ln3_g + i * DD, ln3_b + i * DD, lno);
  }
}